// Round 10
// baseline (450.536 us; speedup 1.0000x reference)
//
#include <hip/hip_runtime.h>
#include <math.h>

#define N_NODES 50000
#define N_EDGES 800000
#define DIM 128
#define PAD 120                 // bucket capacity; realized max degree ~45

// R19 bucket build constraints (carried from R4/R17):
//  - no global atomics (same-address chains @188ns serialize)
//  - single-block line ownership for every global write (else 64B/8B wb amp)
//  - seg-chunks >= ~5 edges so binbuf reads stay line-efficient
#define EPB 1024                // edges per phase-A block
#define NBLKA 782               // ceil(800000/1024)
#define BIN_SHIFT 8
#define NBIN 196                // ceil(50000/256); bin = dst>>8
#define HISTW 197               // per-block stored scan: base[0..196]
#define PREP_BLOCKS 576         // 576*256 = 9*128*128 WTg elements
#define GEMM_BLOCKS 391         // 391 blocks * 8 waves * 16 rows >= 50000

typedef __attribute__((ext_vector_type(8))) short short8;
typedef __attribute__((ext_vector_type(4))) float floatx4;

// f32 -> bf16 bits, round-to-nearest-even (matches v_cvt / numpy)
__device__ __forceinline__ unsigned short f32_to_bf16(float f) {
    unsigned int u = __float_as_uint(f);
    u += 0x7fffu + ((u >> 16) & 1u);
    return (unsigned short)(u >> 16);
}
__device__ __forceinline__ float bf16_to_f32(unsigned short h) {
    return __uint_as_float((unsigned int)h << 16);
}

// R21: non-temporal (evict-first) loads for the gather's zero-reuse streams.
// Scalar 64/32-bit forms only (defensive: no vector-type builtin reliance).
__device__ __forceinline__ int2 ldnt_i2(const int2* p) {
    unsigned long long v = __builtin_nontemporal_load((const unsigned long long*)p);
    int2 r; r.x = (int)(unsigned)(v & 0xffffffffull); r.y = (int)(unsigned)(v >> 32);
    return r;
}

// R18 XOR-swizzled LDS addressing (no pad, LDS 40960 B). Bank spread:
// start-bank = 4*((blk^(row&7))&7) -> 8 lanes per 4-bank window (structural
// minimum for wave64 b128, same as the padded layout it replaced).
__device__ __forceinline__ int swz(int row, int blk) {   // -> short index
    return row * 128 + (((blk ^ (row & 7)) & 15) << 3);
}

// ---------------- fat: block-local LDS counting sort || prep ---------------
// Blocks < NBLKA: sort 1024 edges by dst-bin in LDS, dump contiguously to
// binbuf (full-line coalesced, block-owned lines -> wb == payload), store
// per-block bin starts to histg. Blocks >= NBLKA: fold all 9 W' matrices
// (cg*W + cm*I, betas compile-time) into transposed bf16 WTg.
__global__ __launch_bounds__(256) void sortprep(const int* __restrict__ src,
                                                const int* __restrict__ dst,
                                                const float* __restrict__ ew,
                                                const float* __restrict__ Wlin,
                                                const float* __restrict__ Wcv,
                                                int* __restrict__ histg,
                                                int2* __restrict__ binbuf,
                                                unsigned short* __restrict__ WTg) {
    if (blockIdx.x >= NBLKA) {             // ---- prep tail (3us, hidden) ----
        int i = (blockIdx.x - NBLKA) * 256 + threadIdx.x;   // < 147456
        int m = i >> 14;          // matrix 0..8
        int n = (i >> 7) & 127;   // output col (= row of WT)
        int k = i & 127;          // input dim
        float v;
        if (m == 0) {
            v = Wlin[k * 128 + n];
        } else {
            int l = m - 1;
            float beta = logf(0.5f / (float)(l + 1) + 1.0f);
            v = beta * Wcv[(size_t)l * 16384 + k * 128 + n]
                + ((n == k) ? (1.0f - beta) : 0.0f);
        }
        WTg[i] = f32_to_bf16(v);
        return;
    }
    __shared__ int hist[NBIN];            // doubles as cursor after scan
    __shared__ int base[NBIN + 1];
    __shared__ int2 sorted[EPB];          // 8 KB
    int tid = threadIdx.x;
    int e0 = blockIdx.x * EPB;
    int n = min(EPB, N_EDGES - e0);
    if (tid < NBIN) hist[tid] = 0;
    __syncthreads();
    // pass 1: histogram of dst bins (LDS atomics, ~5-deep chains)
    for (int i = tid; i < n; i += 256) atomicAdd(&hist[dst[e0 + i] >> BIN_SHIFT], 1);
    __syncthreads();
    // exclusive scan base[0..196] (197 entries <= 256 threads: one Hillis)
    if (tid < NBIN) base[tid + 1] = hist[tid];
    if (tid == 0) base[0] = 0;
    __syncthreads();
    for (int off = 1; off < NBIN + 1; off <<= 1) {
        int v = 0;
        if (tid >= off && tid <= NBIN) v = base[tid - off];
        __syncthreads();
        if (tid >= off && tid <= NBIN) base[tid] += v;
        __syncthreads();
    }
    if (tid < NBIN) hist[tid] = base[tid];    // cur = base (reuse hist)
    __syncthreads();
    // pass 2: scatter into LDS sorted order (dst re-read is cache-hot)
    for (int i = tid; i < n; i += 256) {
        int e = e0 + i;
        int d = dst[e];
        int pos = atomicAdd(&hist[d >> BIN_SHIFT], 1);
        int2 p;
        p.x = (src[e] & 0xFFFF) | (d << 16);   // src<65536, d<65536
        p.y = __float_as_int(ew[e]);
        sorted[pos] = p;
    }
    __syncthreads();
    // contiguous dump: full-line coalesced writes, block-exclusive lines
    for (int k = tid; k < n; k += 256)
        binbuf[(size_t)blockIdx.x * EPB + k] = sorted[k];
    if (tid <= NBIN) histg[blockIdx.x * HISTW + tid] = base[tid];
}

// ---------------- fatB: bin-local distribute || x0 GEMM --------------------
// R20: bin_scatter (196 blocks, latency-bound) and gemm_x0 are independent
// -> one 587-block dispatch. No global atomics / no random-line writebacks
// on the scatter side, so the R2 fusion-interference mode does not apply.
// binbuf lives in hB2 (dead until layer 1) so no race with x0B writes.
__global__ __launch_bounds__(512) void fatB(const int* __restrict__ histg,
                                            const int2* __restrict__ binbuf,
                                            int* __restrict__ cnt,
                                            int2* __restrict__ bucket,
                                            const float* __restrict__ x,
                                            const unsigned short* __restrict__ WTg,
                                            const float* __restrict__ bias,
                                            unsigned short* __restrict__ x0B) {
    __shared__ unsigned short WT[128][136];   // gemm blocks only
    __shared__ int c[256];                    // scatter blocks only
    int tid = threadIdx.x;
    if (blockIdx.x < NBIN) {
        // ---- scatter: one block per bin (256 nodes); thread t owns segs
        // t, t+512. Two histg reads per seg (L2-resident strided 4B reads);
        // binbuf read once, contiguous per chunk. Bucket writes confined to
        // the bin's 240KB window from one block -> write-combined.
        int bin = blockIdx.x;
        if (tid < 256) c[tid] = 0;
        __syncthreads();
        for (int t = tid; t < NBLKA; t += 512) {
            int bs = histg[t * HISTW + bin];
            int be = histg[t * HISTW + bin + 1];
            const int2* sp = binbuf + (size_t)t * EPB;
            for (int k = bs; k < be; k++) {
                int2 p = sp[k];
                int d = ((unsigned)p.x) >> 16;
                int pos = atomicAdd(&c[d & 255], 1);
                if (pos < PAD) {               // realized max degree ~45, safe
                    int2 q; q.x = p.x & 0xFFFF; q.y = p.y;
                    bucket[(size_t)d * PAD + pos] = q;
                }
            }
        }
        __syncthreads();
        int node0 = bin << BIN_SHIFT;
        if (tid < 256 && node0 + tid < N_NODES)
            cnt[node0 + tid] = min(c[tid], PAD);
        return;
    }
    // ---- x0 = relu(x @ W_lin + b) -> bf16 rows; 8 waves x 16-row tiles ----
    for (int idx = tid; idx < 2048; idx += 512) {
        int n = idx >> 4, cc = idx & 15;
        *(short8*)(void*)&WT[n][cc * 8] =
            *(const short8*)(const void*)(WTg + n * 128 + cc * 8);
    }
    __syncthreads();
    int wave = tid >> 6;
    int lane = tid & 63;
    int r0 = ((blockIdx.x - NBIN) * 8 + wave) * 16;
    if (r0 >= N_NODES) return;                 // last 3 waves of last block
    int mrow = lane & 15;
    int quad = lane >> 4;
    floatx4 acc[8];
#pragma unroll
    for (int t = 0; t < 8; t++) acc[t] = {0.f, 0.f, 0.f, 0.f};
#pragma unroll
    for (int k0 = 0; k0 < 128; k0 += 32) {
        const float* arow = x + (size_t)(r0 + mrow) * DIM;
        floatx4 alo = *(const floatx4*)(const void*)(arow + k0 + quad * 8);
        floatx4 ahi = *(const floatx4*)(const void*)(arow + k0 + quad * 8 + 4);
        short8 a;
#pragma unroll
        for (int j = 0; j < 4; j++) a[j] = (short)f32_to_bf16(alo[j]);
#pragma unroll
        for (int j = 0; j < 4; j++) a[4 + j] = (short)f32_to_bf16(ahi[j]);
#pragma unroll
        for (int t = 0; t < 8; t++) {
            short8 b = *(const short8*)(const void*)(&WT[t * 16 + mrow][k0 + quad * 8]);
            acc[t] = __builtin_amdgcn_mfma_f32_16x16x32_bf16(a, b, acc[t], 0, 0, 0);
        }
    }
    // C/D layout: col = lane&15, row = quad*4 + i  [verified m89/m91]
#pragma unroll
    for (int t = 0; t < 8; t++) {
        int col = t * 16 + mrow;
        float bv = bias[col];
#pragma unroll
        for (int i = 0; i < 4; i++) {
            int row = r0 + quad * 4 + i;
            float v = fmaxf(acc[t][i] + bv, 0.f);
            x0B[(size_t)row * DIM + col] = f32_to_bf16(v);
        }
    }
}

// ---------------- fused SpMM + residual mix + GEMM (one dispatch/layer) ----
// R21: NT (evict-first) hints on the zero-reuse streams (bucket ep, cnt,
// x0B mix read) to stop them thrashing L2 away from hB rows (the only
// reused data: 16x avg reuse, FETCH 88MB vs 12.8MB set = 6.3x refetch).
// hB row loads stay cached. Gather structure itself unchanged (at floor
// per R5/R6: occupancy-insensitive, 2.59 TB/s L2-miss service).
__global__ __launch_bounds__(512, 4) void layer_fused(
        const unsigned short* __restrict__ hB,
        const unsigned short* __restrict__ x0B,
        const int* __restrict__ cnt,
        const int2* __restrict__ bucket,
        const unsigned short* __restrict__ WTg,
        float* __restrict__ outF,
        unsigned short* __restrict__ outB) {
    __shared__ unsigned short WT[128 * 128];  // swizzled, no pad (32768 B)
    __shared__ unsigned short M[32 * 128];    // swizzled, no pad (8192 B)
    int tid = threadIdx.x;
    for (int idx = tid; idx < 2048; idx += 512) {
        int n = idx >> 4, c = idx & 15;
        *(short8*)(void*)&WT[swz(n, c)] =
            *(const short8*)(const void*)(WTg + n * 128 + c * 8);
    }
    int wave = tid >> 6;
    int lane = tid & 63;
    int eg = lane >> 4;               // edge group 0..3
    int fb = (lane & 15) * 8;         // feature octet
    int r0 = blockIdx.x * 32;

    for (int s = 0; s < 4; s++) {
        int row = (wave << 2) + s;    // 0..31, unique per (wave,s)
        int node = r0 + row;
        float acc[8] = {0.f, 0.f, 0.f, 0.f, 0.f, 0.f, 0.f, 0.f};
        if (node < N_NODES) {
            int end = min(__builtin_nontemporal_load(cnt + node), PAD);
            if (end > 0) {
                const int2* ep = bucket + (size_t)node * PAD;
                int last = end - 1;
                for (int i = 0; i < end; i += 16) {
                    int i0 = i + eg, i1 = i0 + 4, i2 = i0 + 8, i3 = i0 + 12;
                    int2 e0 = ldnt_i2(ep + min(i0, last));
                    int2 e1 = ldnt_i2(ep + min(i1, last));
                    int2 e2 = ldnt_i2(ep + min(i2, last));
                    int2 e3 = ldnt_i2(ep + min(i3, last));
                    short8 r0v = *(const short8*)(const void*)(hB + (size_t)e0.x * DIM + fb);
                    short8 r1v = *(const short8*)(const void*)(hB + (size_t)e1.x * DIM + fb);
                    short8 r2v = *(const short8*)(const void*)(hB + (size_t)e2.x * DIM + fb);
                    short8 r3v = *(const short8*)(const void*)(hB + (size_t)e3.x * DIM + fb);
                    float w0 = (i0 < end) ? __int_as_float(e0.y) : 0.f;
                    float w1 = (i1 < end) ? __int_as_float(e1.y) : 0.f;
                    float w2 = (i2 < end) ? __int_as_float(e2.y) : 0.f;
                    float w3 = (i3 < end) ? __int_as_float(e3.y) : 0.f;
#pragma unroll
                    for (int j = 0; j < 8; j++) {
                        acc[j] = fmaf(w0, bf16_to_f32((unsigned short)r0v[j]), acc[j]);
                        acc[j] = fmaf(w1, bf16_to_f32((unsigned short)r1v[j]), acc[j]);
                        acc[j] = fmaf(w2, bf16_to_f32((unsigned short)r2v[j]), acc[j]);
                        acc[j] = fmaf(w3, bf16_to_f32((unsigned short)r3v[j]), acc[j]);
                    }
                }
            }
        }
        // reduce the 4 edge groups into lanes 0..15
#pragma unroll
        for (int j = 0; j < 8; j++) {
            acc[j] += __shfl_down(acc[j], 32);
            acc[j] += __shfl_down(acc[j], 16);
        }
        if (lane < 16) {
            short8 o;
            if (node < N_NODES) {
                // x0B mix read: once per node per layer, zero intra-layer
                // reuse -> NT via two 64-bit evict-first loads
                const unsigned long long* xp =
                    (const unsigned long long*)(x0B + (size_t)node * DIM + fb);
                unsigned long long xlo = __builtin_nontemporal_load(xp);
                unsigned long long xhi = __builtin_nontemporal_load(xp + 1);
#pragma unroll
                for (int j = 0; j < 8; j++) {
                    unsigned short xb = (unsigned short)(((j < 4 ? xlo : xhi)
                                          >> (16 * (j & 3))) & 0xffffull);
                    o[j] = (short)f32_to_bf16(0.9f * acc[j] + 0.1f * bf16_to_f32(xb));
                }
            } else {
#pragma unroll
                for (int j = 0; j < 8; j++) o[j] = 0;
            }
            *(short8*)(void*)&M[swz(row, lane & 15)] = o;
        }
    }
    __syncthreads();

    // ---- GEMM tail: out = relu(M @ W') ; 8 waves cover 2x8 16x16 tiles ----
    int mrow = lane & 15;
    int quad = lane >> 4;
    int rt = wave >> 2;               // row tile 0..1
    int ctb = (wave & 3) * 2;         // col tile base 0,2,4,6
    floatx4 acc2[2];
    acc2[0] = {0.f, 0.f, 0.f, 0.f};
    acc2[1] = {0.f, 0.f, 0.f, 0.f};
#pragma unroll
    for (int k0 = 0; k0 < 128; k0 += 32) {
        short8 a = *(const short8*)(const void*)(&M[swz(rt * 16 + mrow, k0 / 8 + quad)]);
#pragma unroll
        for (int t = 0; t < 2; t++) {
            short8 b = *(const short8*)(const void*)(&WT[swz((ctb + t) * 16 + mrow, k0 / 8 + quad)]);
            acc2[t] = __builtin_amdgcn_mfma_f32_16x16x32_bf16(a, b, acc2[t], 0, 0, 0);
        }
    }
#pragma unroll
    for (int t = 0; t < 2; t++) {
        int col = (ctb + t) * 16 + mrow;
#pragma unroll
        for (int i = 0; i < 4; i++) {
            int row = r0 + rt * 16 + quad * 4 + i;
            if (row < N_NODES) {
                float v = fmaxf(acc2[t][i], 0.f);
                size_t off = (size_t)row * DIM + col;
                if (outF) outF[off] = v;
                if (outB) outB[off] = f32_to_bf16(v);
            }
        }
    }
}

// ---------------- launch ----------------

extern "C" void kernel_launch(void* const* d_in, const int* in_sizes, int n_in,
                              void* d_out, int out_size, void* d_ws, size_t ws_size,
                              hipStream_t stream) {
    const float* x    = (const float*)d_in[0];
    const float* ew   = (const float*)d_in[1];
    const float* Wlin = (const float*)d_in[2];
    const float* blin = (const float*)d_in[3];
    const float* Wcv  = (const float*)d_in[4];
    const int* eidx = (const int*)d_in[5];
    const int* esrc = eidx;
    const int* edst = eidx + N_EDGES;
    float* out = (float*)d_out;

    char* ws = (char*)d_ws;
    unsigned short* x0B = (unsigned short*)(ws);             // 12.8 MB bf16 x0
    unsigned short* hA  = (unsigned short*)(ws + 12800000);  // 12.8 MB bf16 h ping
    unsigned short* hB2 = (unsigned short*)(ws + 25600000);  // 12.8 MB bf16 h pong
    int* cnt            = (int*)(ws + 38400000);             // N*4 degree
    int2* bucket        = (int2*)(ws + 38600064);            // N*PAD*8 = 48.0 MB
    unsigned short* WTg = (unsigned short*)(ws + 86600064);  // 288 KB
    int* histg          = (int*)(ws + 86894976);             // 782*197*4 = 616 KB
    // binbuf (6.4 MB) overlaps hB2: dead after fatB, first rewritten by
    // layer 1 -> fatB's gemm half can write x0B with no race.
    int2* binbuf        = (int2*)hB2;
    // total ~87.5 MB (under 89.8 MB known-good footprint)

    // sort (782 blocks) || prep (576 blocks): one dispatch
    sortprep<<<NBLKA + PREP_BLOCKS, 256, 0, stream>>>(esrc, edst, ew, Wlin, Wcv,
                                                      histg, binbuf, WTg);

    // distribute (196 blocks) || x0 gemm (391 blocks): one dispatch
    fatB<<<NBIN + GEMM_BLOCKS, 512, 0, stream>>>(histg, binbuf, cnt, bucket,
                                                 x, WTg, blin, x0B);

    const unsigned short* hin = x0B;
    for (int l = 0; l < 8; l++) {
        unsigned short* hout = (l == 7) ? nullptr : ((l & 1) ? hB2 : hA);
        layer_fused<<<1563, 512, 0, stream>>>(hin, x0B, cnt, bucket,
                                              WTg + (size_t)(1 + l) * 16384,
                                              (l == 7) ? out : nullptr, hout);
        hin = hout;
    }
}

// Round 11
// 448.420 us; speedup vs baseline: 1.0047x; 1.0047x over previous
//
#include <hip/hip_runtime.h>
#include <math.h>

#define N_NODES 50000
#define N_EDGES 800000
#define DIM 128
#define PAD 120                 // bucket capacity; realized max degree ~45

// R19 bucket build constraints (carried from R4/R17):
//  - no global atomics (same-address chains @188ns serialize)
//  - single-block line ownership for every global write (else 64B/8B wb amp)
//  - seg-chunks >= ~5 edges so binbuf reads stay line-efficient
#define EPB 1024                // edges per phase-A block
#define NBLKA 782               // ceil(800000/1024)
#define BIN_SHIFT 8
#define NBIN 196                // ceil(50000/256); bin = dst>>8
#define HISTW 197               // per-block stored scan: base[0..196]
#define PREP_BLOCKS 576         // 576*256 = 9*128*128 WTg elements
#define GEMM_BLOCKS 391         // 391 blocks * 8 waves * 16 rows >= 50000

typedef __attribute__((ext_vector_type(8))) short short8;
typedef __attribute__((ext_vector_type(4))) float floatx4;

// f32 -> bf16 bits, round-to-nearest-even (matches v_cvt / numpy)
__device__ __forceinline__ unsigned short f32_to_bf16(float f) {
    unsigned int u = __float_as_uint(f);
    u += 0x7fffu + ((u >> 16) & 1u);
    return (unsigned short)(u >> 16);
}
__device__ __forceinline__ float bf16_to_f32(unsigned short h) {
    return __uint_as_float((unsigned int)h << 16);
}

// R18 XOR-swizzled LDS addressing (no pad, LDS 40960 B). Bank spread:
// start-bank = 4*((blk^(row&7))&7) -> 8 lanes per 4-bank window (structural
// minimum for wave64 b128, same as the padded layout it replaced).
// R22: NT-hint experiment REVERTED (R10: bucket lines have intra-line reuse
// -- 8 edges/line over 2 iterations x 4 eg-groups; evict-first cost +2-4us).
__device__ __forceinline__ int swz(int row, int blk) {   // -> short index
    return row * 128 + (((blk ^ (row & 7)) & 15) << 3);
}

// ---------------- fat: block-local LDS counting sort || prep ---------------
// Blocks < NBLKA: sort 1024 edges by dst-bin in LDS, dump contiguously to
// binbuf (full-line coalesced, block-owned lines -> wb == payload), store
// per-block bin starts to histg. Blocks >= NBLKA: fold all 9 W' matrices
// (cg*W + cm*I, betas compile-time) into transposed bf16 WTg.
__global__ __launch_bounds__(256) void sortprep(const int* __restrict__ src,
                                                const int* __restrict__ dst,
                                                const float* __restrict__ ew,
                                                const float* __restrict__ Wlin,
                                                const float* __restrict__ Wcv,
                                                int* __restrict__ histg,
                                                int2* __restrict__ binbuf,
                                                unsigned short* __restrict__ WTg) {
    if (blockIdx.x >= NBLKA) {             // ---- prep tail (3us, hidden) ----
        int i = (blockIdx.x - NBLKA) * 256 + threadIdx.x;   // < 147456
        int m = i >> 14;          // matrix 0..8
        int n = (i >> 7) & 127;   // output col (= row of WT)
        int k = i & 127;          // input dim
        float v;
        if (m == 0) {
            v = Wlin[k * 128 + n];
        } else {
            int l = m - 1;
            float beta = logf(0.5f / (float)(l + 1) + 1.0f);
            v = beta * Wcv[(size_t)l * 16384 + k * 128 + n]
                + ((n == k) ? (1.0f - beta) : 0.0f);
        }
        WTg[i] = f32_to_bf16(v);
        return;
    }
    __shared__ int hist[NBIN];            // doubles as cursor after scan
    __shared__ int base[NBIN + 1];
    __shared__ int2 sorted[EPB];          // 8 KB
    int tid = threadIdx.x;
    int e0 = blockIdx.x * EPB;
    int n = min(EPB, N_EDGES - e0);
    if (tid < NBIN) hist[tid] = 0;
    __syncthreads();
    // pass 1: histogram of dst bins (LDS atomics, ~5-deep chains)
    for (int i = tid; i < n; i += 256) atomicAdd(&hist[dst[e0 + i] >> BIN_SHIFT], 1);
    __syncthreads();
    // exclusive scan base[0..196] (197 entries <= 256 threads: one Hillis)
    if (tid < NBIN) base[tid + 1] = hist[tid];
    if (tid == 0) base[0] = 0;
    __syncthreads();
    for (int off = 1; off < NBIN + 1; off <<= 1) {
        int v = 0;
        if (tid >= off && tid <= NBIN) v = base[tid - off];
        __syncthreads();
        if (tid >= off && tid <= NBIN) base[tid] += v;
        __syncthreads();
    }
    if (tid < NBIN) hist[tid] = base[tid];    // cur = base (reuse hist)
    __syncthreads();
    // pass 2: scatter into LDS sorted order (dst re-read is cache-hot)
    for (int i = tid; i < n; i += 256) {
        int e = e0 + i;
        int d = dst[e];
        int pos = atomicAdd(&hist[d >> BIN_SHIFT], 1);
        int2 p;
        p.x = (src[e] & 0xFFFF) | (d << 16);   // src<65536, d<65536
        p.y = __float_as_int(ew[e]);
        sorted[pos] = p;
    }
    __syncthreads();
    // contiguous dump: full-line coalesced writes, block-exclusive lines
    for (int k = tid; k < n; k += 256)
        binbuf[(size_t)blockIdx.x * EPB + k] = sorted[k];
    if (tid <= NBIN) histg[blockIdx.x * HISTW + tid] = base[tid];
}

// ---------------- fatB: bin-local distribute || x0 GEMM --------------------
// R20: bin_scatter (196 blocks, latency-bound) and gemm_x0 are independent
// -> one 587-block dispatch. No global atomics / no random-line writebacks
// on the scatter side, so the R2 fusion-interference mode does not apply.
// binbuf lives in hB2 (dead until layer 1) so no race with x0B writes.
__global__ __launch_bounds__(512) void fatB(const int* __restrict__ histg,
                                            const int2* __restrict__ binbuf,
                                            int* __restrict__ cnt,
                                            int2* __restrict__ bucket,
                                            const float* __restrict__ x,
                                            const unsigned short* __restrict__ WTg,
                                            const float* __restrict__ bias,
                                            unsigned short* __restrict__ x0B) {
    __shared__ unsigned short WT[128][136];   // gemm blocks only
    __shared__ int c[256];                    // scatter blocks only
    int tid = threadIdx.x;
    if (blockIdx.x < NBIN) {
        // ---- scatter: one block per bin (256 nodes); thread t owns segs
        // t, t+512. Two histg reads per seg (L2-resident strided 4B reads);
        // binbuf read once, contiguous per chunk. Bucket writes confined to
        // the bin's 240KB window from one block -> write-combined.
        int bin = blockIdx.x;
        if (tid < 256) c[tid] = 0;
        __syncthreads();
        for (int t = tid; t < NBLKA; t += 512) {
            int bs = histg[t * HISTW + bin];
            int be = histg[t * HISTW + bin + 1];
            const int2* sp = binbuf + (size_t)t * EPB;
            for (int k = bs; k < be; k++) {
                int2 p = sp[k];
                int d = ((unsigned)p.x) >> 16;
                int pos = atomicAdd(&c[d & 255], 1);
                if (pos < PAD) {               // realized max degree ~45, safe
                    int2 q; q.x = p.x & 0xFFFF; q.y = p.y;
                    bucket[(size_t)d * PAD + pos] = q;
                }
            }
        }
        __syncthreads();
        int node0 = bin << BIN_SHIFT;
        if (tid < 256 && node0 + tid < N_NODES)
            cnt[node0 + tid] = min(c[tid], PAD);
        return;
    }
    // ---- x0 = relu(x @ W_lin + b) -> bf16 rows; 8 waves x 16-row tiles ----
    for (int idx = tid; idx < 2048; idx += 512) {
        int n = idx >> 4, cc = idx & 15;
        *(short8*)(void*)&WT[n][cc * 8] =
            *(const short8*)(const void*)(WTg + n * 128 + cc * 8);
    }
    __syncthreads();
    int wave = tid >> 6;
    int lane = tid & 63;
    int r0 = ((blockIdx.x - NBIN) * 8 + wave) * 16;
    if (r0 >= N_NODES) return;                 // last 3 waves of last block
    int mrow = lane & 15;
    int quad = lane >> 4;
    floatx4 acc[8];
#pragma unroll
    for (int t = 0; t < 8; t++) acc[t] = {0.f, 0.f, 0.f, 0.f};
#pragma unroll
    for (int k0 = 0; k0 < 128; k0 += 32) {
        const float* arow = x + (size_t)(r0 + mrow) * DIM;
        floatx4 alo = *(const floatx4*)(const void*)(arow + k0 + quad * 8);
        floatx4 ahi = *(const floatx4*)(const void*)(arow + k0 + quad * 8 + 4);
        short8 a;
#pragma unroll
        for (int j = 0; j < 4; j++) a[j] = (short)f32_to_bf16(alo[j]);
#pragma unroll
        for (int j = 0; j < 4; j++) a[4 + j] = (short)f32_to_bf16(ahi[j]);
#pragma unroll
        for (int t = 0; t < 8; t++) {
            short8 b = *(const short8*)(const void*)(&WT[t * 16 + mrow][k0 + quad * 8]);
            acc[t] = __builtin_amdgcn_mfma_f32_16x16x32_bf16(a, b, acc[t], 0, 0, 0);
        }
    }
    // C/D layout: col = lane&15, row = quad*4 + i  [verified m89/m91]
#pragma unroll
    for (int t = 0; t < 8; t++) {
        int col = t * 16 + mrow;
        float bv = bias[col];
#pragma unroll
        for (int i = 0; i < 4; i++) {
            int row = r0 + quad * 4 + i;
            float v = fmaxf(acc[t][i] + bv, 0.f);
            x0B[(size_t)row * DIM + col] = f32_to_bf16(v);
        }
    }
}

// ---------------- fused SpMM + residual mix + GEMM (one dispatch/layer) ----
// AT FLOOR (R5/R6/R8/R10 evidence): 44.7us; insensitive to occupancy (R6),
// cache policy (R10 NT reverted), LDS conflicts (R18). 0.117 lines/cyc/CU
// random-line service, 2.59 TB/s L2-miss BW, FETCH 88MB vs 12.8MB working
// set (inherent random re-fetch: set > per-XCD 4MB L2). Do not touch.
__global__ __launch_bounds__(512, 4) void layer_fused(
        const unsigned short* __restrict__ hB,
        const unsigned short* __restrict__ x0B,
        const int* __restrict__ cnt,
        const int2* __restrict__ bucket,
        const unsigned short* __restrict__ WTg,
        float* __restrict__ outF,
        unsigned short* __restrict__ outB) {
    __shared__ unsigned short WT[128 * 128];  // swizzled, no pad (32768 B)
    __shared__ unsigned short M[32 * 128];    // swizzled, no pad (8192 B)
    int tid = threadIdx.x;
    for (int idx = tid; idx < 2048; idx += 512) {
        int n = idx >> 4, c = idx & 15;
        *(short8*)(void*)&WT[swz(n, c)] =
            *(const short8*)(const void*)(WTg + n * 128 + c * 8);
    }
    int wave = tid >> 6;
    int lane = tid & 63;
    int eg = lane >> 4;               // edge group 0..3
    int fb = (lane & 15) * 8;         // feature octet
    int r0 = blockIdx.x * 32;

    for (int s = 0; s < 4; s++) {
        int row = (wave << 2) + s;    // 0..31, unique per (wave,s)
        int node = r0 + row;
        float acc[8] = {0.f, 0.f, 0.f, 0.f, 0.f, 0.f, 0.f, 0.f};
        if (node < N_NODES) {
            int end = min(cnt[node], PAD);
            if (end > 0) {
                const int2* ep = bucket + (size_t)node * PAD;
                int last = end - 1;
                for (int i = 0; i < end; i += 16) {
                    int i0 = i + eg, i1 = i0 + 4, i2 = i0 + 8, i3 = i0 + 12;
                    int2 e0 = ep[min(i0, last)];
                    int2 e1 = ep[min(i1, last)];
                    int2 e2 = ep[min(i2, last)];
                    int2 e3 = ep[min(i3, last)];
                    short8 r0v = *(const short8*)(const void*)(hB + (size_t)e0.x * DIM + fb);
                    short8 r1v = *(const short8*)(const void*)(hB + (size_t)e1.x * DIM + fb);
                    short8 r2v = *(const short8*)(const void*)(hB + (size_t)e2.x * DIM + fb);
                    short8 r3v = *(const short8*)(const void*)(hB + (size_t)e3.x * DIM + fb);
                    float w0 = (i0 < end) ? __int_as_float(e0.y) : 0.f;
                    float w1 = (i1 < end) ? __int_as_float(e1.y) : 0.f;
                    float w2 = (i2 < end) ? __int_as_float(e2.y) : 0.f;
                    float w3 = (i3 < end) ? __int_as_float(e3.y) : 0.f;
#pragma unroll
                    for (int j = 0; j < 8; j++) {
                        acc[j] = fmaf(w0, bf16_to_f32((unsigned short)r0v[j]), acc[j]);
                        acc[j] = fmaf(w1, bf16_to_f32((unsigned short)r1v[j]), acc[j]);
                        acc[j] = fmaf(w2, bf16_to_f32((unsigned short)r2v[j]), acc[j]);
                        acc[j] = fmaf(w3, bf16_to_f32((unsigned short)r3v[j]), acc[j]);
                    }
                }
            }
        }
        // reduce the 4 edge groups into lanes 0..15
#pragma unroll
        for (int j = 0; j < 8; j++) {
            acc[j] += __shfl_down(acc[j], 32);
            acc[j] += __shfl_down(acc[j], 16);
        }
        if (lane < 16) {
            short8 o;
            if (node < N_NODES) {
                short8 xv = *(const short8*)(const void*)(x0B + (size_t)node * DIM + fb);
#pragma unroll
                for (int j = 0; j < 8; j++)
                    o[j] = (short)f32_to_bf16(0.9f * acc[j]
                                              + 0.1f * bf16_to_f32((unsigned short)xv[j]));
            } else {
#pragma unroll
                for (int j = 0; j < 8; j++) o[j] = 0;
            }
            *(short8*)(void*)&M[swz(row, lane & 15)] = o;
        }
    }
    __syncthreads();

    // ---- GEMM tail: out = relu(M @ W') ; 8 waves cover 2x8 16x16 tiles ----
    int mrow = lane & 15;
    int quad = lane >> 4;
    int rt = wave >> 2;               // row tile 0..1
    int ctb = (wave & 3) * 2;         // col tile base 0,2,4,6
    floatx4 acc2[2];
    acc2[0] = {0.f, 0.f, 0.f, 0.f};
    acc2[1] = {0.f, 0.f, 0.f, 0.f};
#pragma unroll
    for (int k0 = 0; k0 < 128; k0 += 32) {
        short8 a = *(const short8*)(const void*)(&M[swz(rt * 16 + mrow, k0 / 8 + quad)]);
#pragma unroll
        for (int t = 0; t < 2; t++) {
            short8 b = *(const short8*)(const void*)(&WT[swz((ctb + t) * 16 + mrow, k0 / 8 + quad)]);
            acc2[t] = __builtin_amdgcn_mfma_f32_16x16x32_bf16(a, b, acc2[t], 0, 0, 0);
        }
    }
#pragma unroll
    for (int t = 0; t < 2; t++) {
        int col = (ctb + t) * 16 + mrow;
#pragma unroll
        for (int i = 0; i < 4; i++) {
            int row = r0 + rt * 16 + quad * 4 + i;
            if (row < N_NODES) {
                float v = fmaxf(acc2[t][i], 0.f);
                size_t off = (size_t)row * DIM + col;
                if (outF) outF[off] = v;
                if (outB) outB[off] = f32_to_bf16(v);
            }
        }
    }
}

// ---------------- launch ----------------

extern "C" void kernel_launch(void* const* d_in, const int* in_sizes, int n_in,
                              void* d_out, int out_size, void* d_ws, size_t ws_size,
                              hipStream_t stream) {
    const float* x    = (const float*)d_in[0];
    const float* ew   = (const float*)d_in[1];
    const float* Wlin = (const float*)d_in[2];
    const float* blin = (const float*)d_in[3];
    const float* Wcv  = (const float*)d_in[4];
    const int* eidx = (const int*)d_in[5];
    const int* esrc = eidx;
    const int* edst = eidx + N_EDGES;
    float* out = (float*)d_out;

    char* ws = (char*)d_ws;
    unsigned short* x0B = (unsigned short*)(ws);             // 12.8 MB bf16 x0
    unsigned short* hA  = (unsigned short*)(ws + 12800000);  // 12.8 MB bf16 h ping
    unsigned short* hB2 = (unsigned short*)(ws + 25600000);  // 12.8 MB bf16 h pong
    int* cnt            = (int*)(ws + 38400000);             // N*4 degree
    int2* bucket        = (int2*)(ws + 38600064);            // N*PAD*8 = 48.0 MB
    unsigned short* WTg = (unsigned short*)(ws + 86600064);  // 288 KB
    int* histg          = (int*)(ws + 86894976);             // 782*197*4 = 616 KB
    // binbuf (6.4 MB) overlaps hB2: dead after fatB, first rewritten by
    // layer 1 -> fatB's gemm half can write x0B with no race.
    int2* binbuf        = (int2*)hB2;
    // total ~87.5 MB (under 89.8 MB known-good footprint)

    // sort (782 blocks) || prep (576 blocks): one dispatch
    sortprep<<<NBLKA + PREP_BLOCKS, 256, 0, stream>>>(esrc, edst, ew, Wlin, Wcv,
                                                      histg, binbuf, WTg);

    // distribute (196 blocks) || x0 gemm (391 blocks): one dispatch
    fatB<<<NBIN + GEMM_BLOCKS, 512, 0, stream>>>(histg, binbuf, cnt, bucket,
                                                 x, WTg, blin, x0B);

    const unsigned short* hin = x0B;
    for (int l = 0; l < 8; l++) {
        unsigned short* hout = (l == 7) ? nullptr : ((l & 1) ? hB2 : hA);
        layer_fused<<<1563, 512, 0, stream>>>(hin, x0B, cnt, bucket,
                                              WTg + (size_t)(1 + l) * 16384,
                                              (l == 7) ? out : nullptr, hout);
        hin = hout;
    }
}